// Round 11
// baseline (2228.528 us; speedup 1.0000x reference)
//
#include <hip/hip_runtime.h>

#define N_NODES 5000
#define NH 8

typedef unsigned short u16;
typedef short bf16x8 __attribute__((ext_vector_type(8)));
typedef float f32x4 __attribute__((ext_vector_type(4)));

static __device__ __forceinline__ float selu_f(float x) {
    const float sc = 1.0507009873554805f;
    const float al = 1.6732632423543772f;
    return x > 0.f ? sc * x : sc * al * (__expf(x) - 1.f);
}

static __device__ __forceinline__ u16 f2bf(float x) {
    union { float f; unsigned u; } v; v.f = x;
    unsigned r = v.u + 0x7fff + ((v.u >> 16) & 1);
    return (u16)(r >> 16);
}

static __device__ __forceinline__ float bf2f(unsigned hi16) {
    union { unsigned u; float f; } v; v.u = hi16 << 16;
    return v.f;
}

// ---------------- CSR build (parallel — proven) ----------------
__global__ void k_count(const int* __restrict__ ei, int* cnt, int E, int Esz) {
    int e = blockIdx.x * 256 + threadIdx.x;
    if (e >= Esz) return;
    int dst = (e < E) ? ei[E + e] : (e - E);
    atomicAdd(&cnt[dst], 1);
}

__global__ void k_scan(const int* __restrict__ cnt, int* __restrict__ rowp, int n) {
    __shared__ int ps[256];
    int t = threadIdx.x;
    int per = (n + 255) / 256;
    int b = t * per;
    int s = 0;
    for (int i = 0; i < per; ++i) { int idx = b + i; if (idx < n) s += cnt[idx]; }
    ps[t] = s;
    __syncthreads();
    for (int off = 1; off < 256; off <<= 1) {
        int v = (t >= off) ? ps[t - off] : 0;
        __syncthreads();
        ps[t] += v;
        __syncthreads();
    }
    int run = (t == 0) ? 0 : ps[t - 1];
    for (int i = 0; i < per; ++i) {
        int idx = b + i;
        if (idx < n) { rowp[idx] = run; run += cnt[idx]; }
    }
    if (t == 255) rowp[n] = run;
}

__global__ void k_fill(const int* __restrict__ ei, const int* __restrict__ rowp,
                       int* cur, int* ssrc, int E, int Esz) {
    int e = blockIdx.x * 256 + threadIdx.x;
    if (e >= Esz) return;
    int src, dst;
    if (e < E) { src = ei[e]; dst = ei[E + e]; }
    else       { src = e - E; dst = src; }
    int pos = rowp[dst] + atomicAdd(&cur[dst], 1);
    ssrc[pos] = src;
}

// ---------------- foldall ----------------
__global__ void k_foldall(const float* W1, const float* W2, const float* W3, const float* W4,
                          const float* s1, const float* s2, const float* s3, const float* s4,
                          const float* d1, const float* d2, const float* d3, const float* d4,
                          float* __restrict__ fsAll, float* __restrict__ fdAll) {
    const int Ks[4] = {258, 516, 262, 136};
    const int Cs[4] = {512, 256, 128, 20};
    int li = blockIdx.y;
    int k = blockIdx.x;
    if (k >= Ks[li]) return;
    const float* W  = (li == 0) ? W1 : (li == 1) ? W2 : (li == 2) ? W3 : W4;
    const float* as = (li == 0) ? s1 : (li == 1) ? s2 : (li == 2) ? s3 : s4;
    const float* ad = (li == 0) ? d1 : (li == 1) ? d2 : (li == 2) ? d3 : d4;
    int C = Cs[li];
    int lane = threadIdx.x;   // 64
    float s[8] = {0.f,0.f,0.f,0.f,0.f,0.f,0.f,0.f};
    float d[8] = {0.f,0.f,0.f,0.f,0.f,0.f,0.f,0.f};
    const float* wr = W + (size_t)k * 8 * C;
    for (int c = lane; c < C; c += 64) {
        #pragma unroll
        for (int h = 0; h < 8; ++h) {
            float w = wr[h * C + c];
            s[h] += w * as[h * C + c];
            d[h] += w * ad[h * C + c];
        }
    }
    #pragma unroll
    for (int off = 32; off >= 1; off >>= 1) {
        #pragma unroll
        for (int h = 0; h < 8; ++h) {
            s[h] += __shfl_xor(s[h], off);
            d[h] += __shfl_xor(d[h], off);
        }
    }
    if (lane == 0) {
        float* fo = fsAll + (size_t)li * 516 * 8 + k * 8;
        float* go = fdAll + (size_t)li * 516 * 8 + k * 8;
        #pragma unroll
        for (int h = 0; h < 8; ++h) { fo[h] = s[h]; go[h] = d[h]; }
    }
}

// ---------------- wtrall ----------------
__global__ __launch_bounds__(256) void k_wtrall(const float* W1, const float* W2, const float* W3,
                                                u16* T1, u16* T2, u16* T3) {
    const int Ks[3] = {258, 516, 262};
    const int Cs[3] = {512, 256, 128};
    const int Kps[3] = {288, 544, 288};
    int li = blockIdx.z;
    int C = Cs[li], K = Ks[li], Kp = Kps[li], KK = 8 * Kp;
    int c0 = blockIdx.x * 32;
    int j0 = blockIdx.y * 32;
    if (c0 >= C || j0 >= KK) return;
    const float* W = (li == 0) ? W1 : (li == 1) ? W2 : W3;
    u16* Wt2 = (li == 0) ? T1 : (li == 1) ? T2 : T3;
    __shared__ float tile[32][33];
    int h = j0 / Kp, k0 = j0 % Kp;
    int tid = threadIdx.x;
    for (int idx = tid; idx < 1024; idx += 256) {
        int kr = idx >> 5, cc = idx & 31;
        int gk = k0 + kr;
        tile[kr][cc] = (gk < K) ? W[(size_t)gk * (8 * C) + h * C + c0 + cc] : 0.f;
    }
    __syncthreads();
    for (int idx = tid; idx < 1024; idx += 256) {
        int cr = idx >> 5, kc = idx & 31;
        Wt2[(size_t)(c0 + cr) * KK + j0 + kc] = f2bf(tile[kc][cr]);
    }
}

// ---------------- grid-wide barrier (agent scope, cross-XCD safe) ----------------
static __device__ __forceinline__ void gbar(int* cnt, int* gen) {
    __syncthreads();
    __threadfence();
    if (threadIdx.x == 0) {
        int g = __hip_atomic_load(gen, __ATOMIC_RELAXED, __HIP_MEMORY_SCOPE_AGENT);
        int prev = __hip_atomic_fetch_add(cnt, 1, __ATOMIC_ACQ_REL, __HIP_MEMORY_SCOPE_AGENT);
        if (prev == (int)gridDim.x - 1) {
            __hip_atomic_store(cnt, 0, __ATOMIC_RELAXED, __HIP_MEMORY_SCOPE_AGENT);
            __hip_atomic_fetch_add(gen, 1, __ATOMIC_ACQ_REL, __HIP_MEMORY_SCOPE_AGENT);
        } else {
            while (__hip_atomic_load(gen, __ATOMIC_ACQUIRE, __HIP_MEMORY_SCOPE_AGENT) == g)
                __builtin_amdgcn_s_sleep(8);
        }
    }
    __syncthreads();
    __threadfence();
}

// ---------------- stage: mf (block-strided nodes) ----------------
static __device__ void dev_mf(const float* p0, const float* p1, const float* p2, const float* p3,
                              int np, const float* data, const float* W0, const float* b0,
                              const u16* facc, const float* biasp, int split, int MN, int FC,
                              int K, int Kp, const float* fs, const float* fd,
                              u16* afb, float* es, float* ed, float* c0out) {
    __shared__ float drow[10];
    __shared__ float red[4][16];
    int t = threadIdx.x;
    bool l1 = (biasp == nullptr);
    for (int n = blockIdx.x; n < N_NODES; n += gridDim.x) {
        if (l1 && t < 10) drow[t] = data[n * 10 + t];
        __syncthreads();
        float pes[8] = {0.f,0.f,0.f,0.f,0.f,0.f,0.f,0.f};
        float ped[8] = {0.f,0.f,0.f,0.f,0.f,0.f,0.f,0.f};
        u16* rowb = afb + (size_t)n * Kp;
        for (int cf = t; cf < FC; cf += 256) {
            float v;
            if (l1) {
                v = b0[cf];
                #pragma unroll
                for (int k = 0; k < 10; ++k) v += drow[k] * W0[k * 256 + cf];
                v = selu_f(v);
            } else {
                float s = 0.f;
                for (int z = 0; z < split; ++z)
                    s += bf2f(facc[(size_t)z * MN + (size_t)n * FC + cf]);
                v = selu_f(s * 0.125f + biasp[cf]);
            }
            int c = 2 * np + cf;
            rowb[c] = f2bf(v);
            const float* fsr = fs + c * 8;
            const float* fdr = fd + c * 8;
            #pragma unroll
            for (int h = 0; h < 8; ++h) { pes[h] += v * fsr[h]; ped[h] += v * fdr[h]; }
        }
        if (t < 2 * np) {
            float v;
            if (l1) {
                v = drow[t];
                c0out[n * 2 + t] = v;
            } else {
                const float* p = (t < 2) ? p0 : (t < 4) ? p1 : (t < 6) ? p2 : p3;
                v = p[n * 2 + (t & 1)];
            }
            rowb[t] = f2bf(v);
            #pragma unroll
            for (int h = 0; h < 8; ++h) { pes[h] += v * fs[t * 8 + h]; ped[h] += v * fd[t * 8 + h]; }
        }
        for (int c = K + t; c < Kp; c += 256) rowb[c] = 0;
        #pragma unroll
        for (int off = 32; off >= 1; off >>= 1) {
            #pragma unroll
            for (int h = 0; h < 8; ++h) {
                pes[h] += __shfl_xor(pes[h], off);
                ped[h] += __shfl_xor(ped[h], off);
            }
        }
        int wv = t >> 6, ln = t & 63;
        if (ln == 0) {
            #pragma unroll
            for (int h = 0; h < 8; ++h) { red[wv][h] = pes[h]; red[wv][8 + h] = ped[h]; }
        }
        __syncthreads();
        if (t < 16) {
            float s = red[0][t] + red[1][t] + red[2][t] + red[3][t];
            if (t < 8) es[n * 8 + t] = s;
            else       ed[n * 8 + (t - 8)] = s;
        }
        __syncthreads();
    }
}

// ---------------- stage: softmax + gather + coords (block-strided nodes) ----------------
template <int S32>
static __device__ void dev_gag(const float* es, const float* ed,
                               const int* rowp, const int* ssrc,
                               const float* cprev, const u16* afb,
                               u16* g, float* cnext, int Kp) {
    __shared__ int   ls[128];
    __shared__ float la[128 * 8];
    __shared__ float lc0[128], lc1[128], lw[128];
    __shared__ float linv[8];
    int t = threadIdx.x;
    for (int n = blockIdx.x; n < N_NODES; n += gridDim.x) {
        int s0 = rowp[n];
        int deg = rowp[n + 1] - s0;
        if (deg > 128) deg = 128;
        for (int i = t; i < deg; i += 256) {
            int src = ssrc[s0 + i];
            ls[i] = src;
            lc0[i] = cprev[src * 2];
            lc1[i] = cprev[src * 2 + 1];
        }
        __syncthreads();
        for (int i = t; i < deg * 8; i += 256) {
            int e = i >> 3, h = i & 7;
            float x = es[ls[e] * 8 + h] + ed[n * 8 + h];
            la[i] = x > 0.f ? x : 0.2f * x;
        }
        __syncthreads();
        if (t < 8) {
            float m = -1e30f;
            for (int e = 0; e < deg; ++e) m = fmaxf(m, la[e * 8 + t]);
            float s = 0.f;
            for (int e = 0; e < deg; ++e) {
                float v = __expf(la[e * 8 + t] - m);
                la[e * 8 + t] = v;
                s += v;
            }
            linv[t] = 1.f / s;
        }
        __syncthreads();
        for (int i = t; i < deg; i += 256) {
            float w = 0.f;
            #pragma unroll
            for (int h = 0; h < 8; ++h) w += la[i * 8 + h] * linv[h];
            lw[i] = w;
        }
        int nW = Kp >> 1;
        float acc[8][2 * S32];
        #pragma unroll
        for (int h = 0; h < 8; ++h)
            #pragma unroll
            for (int s = 0; s < 2 * S32; ++s) acc[h][s] = 0.f;
        int e = 0;
        for (; e + 1 < deg; e += 2) {
            const unsigned* r0 = (const unsigned*)(afb + (size_t)ls[e] * Kp);
            const unsigned* r1 = (const unsigned*)(afb + (size_t)ls[e + 1] * Kp);
            unsigned v0[S32], v1[S32];
            #pragma unroll
            for (int s = 0; s < S32; ++s) {
                int w = t + 256 * s;
                v0[s] = (w < nW) ? r0[w] : 0u;
                v1[s] = (w < nW) ? r1[w] : 0u;
            }
            float a0[8], a1[8];
            #pragma unroll
            for (int h = 0; h < 8; ++h) { a0[h] = la[e * 8 + h]; a1[h] = la[(e + 1) * 8 + h]; }
            #pragma unroll
            for (int s = 0; s < S32; ++s) {
                float x0 = bf2f(v0[s] & 0xffff), y0 = bf2f(v0[s] >> 16);
                float x1 = bf2f(v1[s] & 0xffff), y1 = bf2f(v1[s] >> 16);
                #pragma unroll
                for (int h = 0; h < 8; ++h) {
                    acc[h][2 * s]     += a0[h] * x0 + a1[h] * x1;
                    acc[h][2 * s + 1] += a0[h] * y0 + a1[h] * y1;
                }
            }
        }
        if (e < deg) {
            const unsigned* r0 = (const unsigned*)(afb + (size_t)ls[e] * Kp);
            unsigned v0[S32];
            #pragma unroll
            for (int s = 0; s < S32; ++s) {
                int w = t + 256 * s;
                v0[s] = (w < nW) ? r0[w] : 0u;
            }
            float a0[8];
            #pragma unroll
            for (int h = 0; h < 8; ++h) a0[h] = la[e * 8 + h];
            #pragma unroll
            for (int s = 0; s < S32; ++s) {
                float x0 = bf2f(v0[s] & 0xffff), y0 = bf2f(v0[s] >> 16);
                #pragma unroll
                for (int h = 0; h < 8; ++h) {
                    acc[h][2 * s]     += a0[h] * x0;
                    acc[h][2 * s + 1] += a0[h] * y0;
                }
            }
        }
        unsigned* grw = (unsigned*)(g + (size_t)n * 8 * Kp);
        #pragma unroll
        for (int s = 0; s < S32; ++s) {
            int w = t + 256 * s;
            if (w < nW) {
                #pragma unroll
                for (int h = 0; h < 8; ++h) {
                    float iv = linv[h];
                    unsigned lo = f2bf(acc[h][2 * s] * iv);
                    unsigned hi = f2bf(acc[h][2 * s + 1] * iv);
                    grw[h * nW + w] = lo | (hi << 16);
                }
            }
        }
        __syncthreads();
        if (t == 0) {
            float oc0 = 0.f, oc1 = 0.f;
            for (int i = 0; i < deg; ++i) { oc0 += lw[i] * lc0[i]; oc1 += lw[i] * lc1[i]; }
            oc0 *= 0.025f; oc1 *= 0.025f;
            float a0 = cprev[n * 2], a1 = cprev[n * 2 + 1];
            cnext[n * 2]     = (a0 == 0.f) ? 0.f : ((a0 == 1.f) ? 1.f : oc0);
            cnext[n * 2 + 1] = (a1 == 1.f) ? 1.f : ((a1 == 0.f) ? 0.f : oc1);
        }
        __syncthreads();
    }
}

// ---------------- stage: split-K MFMA GEMM (job-strided 128x128 tiles) ----------------
static __device__ void dev_gemm(const u16* A, const u16* Bt, u16* facc16,
                                int KK, int NC, int njX, int split, int kchunk, int MN) {
    __shared__ u16 As[128 * 32];
    __shared__ u16 Bs[128 * 32];
    const int M = N_NODES;
    int tid = threadIdx.x;
    int wave = tid >> 6, lane = tid & 63;
    int wm = (wave >> 1) * 64, wn = (wave & 1) * 64;
    int l16 = lane & 15, q = lane >> 4;
    int njobs = njX * 40 * split;
    for (int job = blockIdx.x; job < njobs; job += gridDim.x) {
        int bx = job % njX;
        int r2 = job / njX;
        int by = r2 % 40;
        int z  = r2 / 40;
        int bm = by * 128, bn = bx * 128;
        int kbeg = z * kchunk, kend = min(KK, kbeg + kchunk);
        f32x4 acc[4][4] = {};
        for (int k0 = kbeg; k0 < kend; k0 += 32) {
            #pragma unroll
            for (int it = 0; it < 2; ++it) {
                int seg = tid + it * 256;
                int row = seg >> 2, sq = seg & 3;
                uint4 va = {0u, 0u, 0u, 0u};
                int grow = bm + row;
                if (grow < M) va = *(const uint4*)(A + (size_t)grow * KK + k0 + sq * 8);
                *(uint4*)(As + row * 32 + ((sq ^ (row & 3)) * 8)) = va;
                uint4 vb = *(const uint4*)(Bt + (size_t)(bn + row) * KK + k0 + sq * 8);
                *(uint4*)(Bs + row * 32 + ((sq ^ (row & 3)) * 8)) = vb;
            }
            __syncthreads();
            bf16x8 fa[4], fb[4];
            #pragma unroll
            for (int mi = 0; mi < 4; ++mi) {
                int row = wm + mi * 16 + l16;
                fa[mi] = *(const bf16x8*)(As + row * 32 + ((q ^ (row & 3)) * 8));
                int col = wn + mi * 16 + l16;
                fb[mi] = *(const bf16x8*)(Bs + col * 32 + ((q ^ (col & 3)) * 8));
            }
            #pragma unroll
            for (int mi = 0; mi < 4; ++mi)
                #pragma unroll
                for (int ni = 0; ni < 4; ++ni)
                    acc[mi][ni] = __builtin_amdgcn_mfma_f32_16x16x32_bf16(fa[mi], fb[ni], acc[mi][ni], 0, 0, 0);
            __syncthreads();
        }
        u16* out = facc16 + (size_t)z * MN;
        #pragma unroll
        for (int mi = 0; mi < 4; ++mi) {
            int row0 = bm + wm + mi * 16 + q * 4;
            #pragma unroll
            for (int ni = 0; ni < 4; ++ni) {
                int col = bn + wn + ni * 16 + l16;
                #pragma unroll
                for (int r = 0; r < 4; ++r) {
                    int row = row0 + r;
                    if (row < M) out[(size_t)row * NC + col] = f2bf(acc[mi][ni][r]);
                }
            }
        }
        __syncthreads();
    }
}

// ---------------- stage: final softmax + coords (wave-strided nodes) ----------------
static __device__ void dev_final(const float* es, const float* ed,
                                 const int* rowp, const int* ssrc,
                                 const float* cprev, float* outp) {
    int gwid = (blockIdx.x * blockDim.x + threadIdx.x) >> 6;
    int nwaves = (gridDim.x * blockDim.x) >> 6;
    int lane = threadIdx.x & 63;
    int h = lane & 7, ei = lane >> 3;
    for (int n = gwid; n < N_NODES; n += nwaves) {
        int s0 = rowp[n], deg = rowp[n + 1] - s0;
        float edh = ed[n * 8 + h];
        float m = -1e30f;
        for (int b = 0; b < deg; b += 8) {
            int e = b + ei;
            if (e < deg) {
                int src = ssrc[s0 + e];
                float x = es[src * 8 + h] + edh;
                x = x > 0.f ? x : 0.2f * x;
                m = fmaxf(m, x);
            }
        }
        m = fmaxf(m, __shfl_xor(m, 8));
        m = fmaxf(m, __shfl_xor(m, 16));
        m = fmaxf(m, __shfl_xor(m, 32));
        float ssum = 0.f;
        for (int b = 0; b < deg; b += 8) {
            int e = b + ei;
            if (e < deg) {
                int src = ssrc[s0 + e];
                float x = es[src * 8 + h] + edh;
                x = x > 0.f ? x : 0.2f * x;
                ssum += __expf(x - m);
            }
        }
        ssum += __shfl_xor(ssum, 8);
        ssum += __shfl_xor(ssum, 16);
        ssum += __shfl_xor(ssum, 32);
        float inv = 1.f / ssum;
        float oc0 = 0.f, oc1 = 0.f;
        for (int b = 0; b < deg; b += 8) {
            int e = b + ei;
            if (e < deg) {
                int src = ssrc[s0 + e];
                float x = es[src * 8 + h] + edh;
                x = x > 0.f ? x : 0.2f * x;
                float w = __expf(x - m) * inv;
                w += __shfl_xor(w, 1);
                w += __shfl_xor(w, 2);
                w += __shfl_xor(w, 4);
                if (h == 0) {
                    oc0 += w * cprev[src * 2];
                    oc1 += w * cprev[src * 2 + 1];
                }
            }
        }
        oc0 += __shfl_xor(oc0, 8);  oc1 += __shfl_xor(oc1, 8);
        oc0 += __shfl_xor(oc0, 16); oc1 += __shfl_xor(oc1, 16);
        oc0 += __shfl_xor(oc0, 32); oc1 += __shfl_xor(oc1, 32);
        if (lane == 0) {
            oc0 *= 0.025f; oc1 *= 0.025f;
            float a0 = cprev[n * 2], a1 = cprev[n * 2 + 1];
            outp[n * 2]     = (a0 == 0.f) ? 0.f : ((a0 == 1.f) ? 1.f : oc0);
            outp[n * 2 + 1] = (a1 == 1.f) ? 1.f : ((a1 == 0.f) ? 0.f : oc1);
        }
    }
}

// ---------------- megakernel: 4 layers + final, grid barriers between stages ----------------
struct MA {
    const float *data, *W0, *b0;
    const float *bs0, *bs1, *bs2;
    const float *fsAll, *fdAll;
    const u16 *T1, *T2, *T3;
    u16 *afb, *g, *facc;
    float *es, *ed;
    float *c0, *c1, *c2, *c3;
    const int *rowp, *ssrc;
    float *outp;
    int *bar, *gen;
};

__global__ __launch_bounds__(256, 2) void k_mega(MA a) {
    const float* fs0 = a.fsAll;             const float* fd0 = a.fdAll;
    const float* fs1 = a.fsAll + 516 * 8;   const float* fd1 = a.fdAll + 516 * 8;
    const float* fs2 = a.fsAll + 2 * 516 * 8; const float* fd2 = a.fdAll + 2 * 516 * 8;
    const float* fs3 = a.fsAll + 3 * 516 * 8; const float* fd3 = a.fdAll + 3 * 516 * 8;

    // Layer 1 (li=0): K=258 Kp=288 C=512 split=4
    dev_mf(a.c0, nullptr, nullptr, nullptr, 1, a.data, a.W0, a.b0,
           a.facc, nullptr, 1, 0, 256, 258, 288, fs0, fd0, a.afb, a.es, a.ed, a.c0);
    gbar(a.bar, a.gen);
    dev_gag<1>(a.es, a.ed, a.rowp, a.ssrc, a.c0, a.afb, a.g, a.c1, 288);
    gbar(a.bar, a.gen);
    dev_gemm(a.g, a.T1, a.facc, 2304, 512, 4, 4, 576, N_NODES * 512);
    gbar(a.bar, a.gen);

    // Layer 2 (li=1): K=516 Kp=544 C=256 split=8; feat from facc(split 4, FC=512)
    dev_mf(a.c1, a.c0, nullptr, nullptr, 2, a.data, a.W0, a.b0,
           a.facc, a.bs0, 4, N_NODES * 512, 512, 516, 544, fs1, fd1, a.afb, a.es, a.ed, nullptr);
    gbar(a.bar, a.gen);
    dev_gag<2>(a.es, a.ed, a.rowp, a.ssrc, a.c1, a.afb, a.g, a.c2, 544);
    gbar(a.bar, a.gen);
    dev_gemm(a.g, a.T2, a.facc, 4352, 256, 2, 8, 544, N_NODES * 256);
    gbar(a.bar, a.gen);

    // Layer 3 (li=2): K=262 Kp=288 C=128 split=8; feat from facc(split 8, FC=256)
    dev_mf(a.c2, a.c1, a.c0, nullptr, 3, a.data, a.W0, a.b0,
           a.facc, a.bs1, 8, N_NODES * 256, 256, 262, 288, fs2, fd2, a.afb, a.es, a.ed, nullptr);
    gbar(a.bar, a.gen);
    dev_gag<1>(a.es, a.ed, a.rowp, a.ssrc, a.c2, a.afb, a.g, a.c3, 288);
    gbar(a.bar, a.gen);
    dev_gemm(a.g, a.T3, a.facc, 2304, 128, 1, 8, 288, N_NODES * 128);
    gbar(a.bar, a.gen);

    // Layer 4 (li=3): logits only; feat from facc(split 8, FC=128)
    dev_mf(a.c3, a.c2, a.c1, a.c0, 4, a.data, a.W0, a.b0,
           a.facc, a.bs2, 8, N_NODES * 128, 128, 136, 160, fs3, fd3, a.afb, a.es, a.ed, nullptr);
    gbar(a.bar, a.gen);
    dev_final(a.es, a.ed, a.rowp, a.ssrc, a.c3, a.outp);
}

extern "C" void kernel_launch(void* const* d_in, const int* in_sizes, int n_in,
                              void* d_out, int out_size, void* d_ws, size_t ws_size,
                              hipStream_t stream) {
    const float* data = (const float*)d_in[0];
    const int* ei = (const int*)d_in[1];
    const float* W0 = (const float*)d_in[2];
    const float* b0 = (const float*)d_in[3];
    int E = in_sizes[1] / 2;
    int Esz = E + N_NODES;

    char* wp = (char*)d_ws;
    size_t off = 0;
    auto alloc = [&](size_t bytes) {
        void* p = wp + off;
        off += (bytes + 1023) & ~(size_t)1023;
        return p;
    };
    u16*   g     = (u16*)alloc((size_t)N_NODES * 8 * 576 * 2);
    u16*   T1    = (u16*)alloc((size_t)512 * 8 * 288 * 2);
    u16*   T2    = (u16*)alloc((size_t)256 * 8 * 544 * 2);
    u16*   T3    = (u16*)alloc((size_t)128 * 8 * 288 * 2);
    u16*   facc  = (u16*)alloc((size_t)8 * N_NODES * 512 * 2);
    u16*   afb   = (u16*)alloc((size_t)N_NODES * 576 * 2);
    float* es    = (float*)alloc((size_t)N_NODES * 8 * 4);
    float* ebd   = (float*)alloc((size_t)N_NODES * 8 * 4);
    float* fsAll = (float*)alloc((size_t)4 * 516 * 8 * 4);
    float* fdAll = (float*)alloc((size_t)4 * 516 * 8 * 4);
    float* c0    = (float*)alloc(N_NODES * 2 * 4);
    float* c1    = (float*)alloc(N_NODES * 2 * 4);
    float* c2    = (float*)alloc(N_NODES * 2 * 4);
    float* c3    = (float*)alloc(N_NODES * 2 * 4);
    int* cnt  = (int*)alloc((N_NODES * 2 + 2) * 4);   // cnt, cur, bar, gen — one memset
    int* cur  = cnt + N_NODES;
    int* bar  = cnt + 2 * N_NODES;
    int* gen  = bar + 1;
    int* rowp = (int*)alloc((N_NODES + 1) * 4);
    int* ssrc = (int*)alloc(Esz * 4);

    hipMemsetAsync(cnt, 0, (N_NODES * 2 + 2) * 4, stream);
    int gE = (Esz + 255) / 256;
    k_count<<<gE, 256, 0, stream>>>(ei, cnt, E, Esz);
    k_scan<<<1, 256, 0, stream>>>(cnt, rowp, N_NODES);
    k_fill<<<gE, 256, 0, stream>>>(ei, rowp, cur, ssrc, E, Esz);

    const float* W1 = (const float*)d_in[4];
    const float* W2 = (const float*)d_in[8];
    const float* W3 = (const float*)d_in[12];
    const float* W4 = (const float*)d_in[16];
    k_foldall<<<dim3(516, 4), 64, 0, stream>>>(W1, W2, W3, W4,
        (const float*)d_in[5], (const float*)d_in[9], (const float*)d_in[13], (const float*)d_in[17],
        (const float*)d_in[6], (const float*)d_in[10], (const float*)d_in[14], (const float*)d_in[18],
        fsAll, fdAll);
    k_wtrall<<<dim3(16, 136, 3), 256, 0, stream>>>(W1, W2, W3, T1, T2, T3);

    MA ma;
    ma.data = data; ma.W0 = W0; ma.b0 = b0;
    ma.bs0 = (const float*)d_in[7];
    ma.bs1 = (const float*)d_in[11];
    ma.bs2 = (const float*)d_in[15];
    ma.fsAll = fsAll; ma.fdAll = fdAll;
    ma.T1 = T1; ma.T2 = T2; ma.T3 = T3;
    ma.afb = afb; ma.g = g; ma.facc = facc;
    ma.es = es; ma.ed = ebd;
    ma.c0 = c0; ma.c1 = c1; ma.c2 = c2; ma.c3 = c3;
    ma.rowp = rowp; ma.ssrc = ssrc;
    ma.outp = (float*)d_out;
    ma.bar = bar; ma.gen = gen;
    k_mega<<<512, 256, 0, stream>>>(ma);
}

// Round 12
// 380.603 us; speedup vs baseline: 5.8553x; 5.8553x over previous
//
#include <hip/hip_runtime.h>

#define N_NODES 5000
#define NH 8

typedef unsigned short u16;
typedef short bf16x8 __attribute__((ext_vector_type(8)));
typedef float f32x4 __attribute__((ext_vector_type(4)));

static __device__ __forceinline__ float selu_f(float x) {
    const float sc = 1.0507009873554805f;
    const float al = 1.6732632423543772f;
    return x > 0.f ? sc * x : sc * al * (__expf(x) - 1.f);
}

static __device__ __forceinline__ u16 f2bf(float x) {
    union { float f; unsigned u; } v; v.f = x;
    unsigned r = v.u + 0x7fff + ((v.u >> 16) & 1);
    return (u16)(r >> 16);
}

static __device__ __forceinline__ float bf2f(unsigned hi16) {
    union { unsigned u; float f; } v; v.u = hi16 << 16;
    return v.f;
}

// ---------------- CSR build (parallel — proven) ----------------
__global__ void k_count(const int* __restrict__ ei, int* cnt, int E, int Esz) {
    int e = blockIdx.x * 256 + threadIdx.x;
    if (e >= Esz) return;
    int dst = (e < E) ? ei[E + e] : (e - E);
    atomicAdd(&cnt[dst], 1);
}

__global__ void k_scan(const int* __restrict__ cnt, int* __restrict__ rowp, int n) {
    __shared__ int ps[256];
    int t = threadIdx.x;
    int per = (n + 255) / 256;
    int b = t * per;
    int s = 0;
    for (int i = 0; i < per; ++i) { int idx = b + i; if (idx < n) s += cnt[idx]; }
    ps[t] = s;
    __syncthreads();
    for (int off = 1; off < 256; off <<= 1) {
        int v = (t >= off) ? ps[t - off] : 0;
        __syncthreads();
        ps[t] += v;
        __syncthreads();
    }
    int run = (t == 0) ? 0 : ps[t - 1];
    for (int i = 0; i < per; ++i) {
        int idx = b + i;
        if (idx < n) { rowp[idx] = run; run += cnt[idx]; }
    }
    if (t == 255) rowp[n] = run;
}

__global__ void k_fill(const int* __restrict__ ei, const int* __restrict__ rowp,
                       int* cur, int* ssrc, int E, int Esz) {
    int e = blockIdx.x * 256 + threadIdx.x;
    if (e >= Esz) return;
    int src, dst;
    if (e < E) { src = ei[e]; dst = ei[E + e]; }
    else       { src = e - E; dst = src; }
    int pos = rowp[dst] + atomicAdd(&cur[dst], 1);
    ssrc[pos] = src;
}

// ---------------- k_prep: fused foldall + wtrall (independent prep, one dispatch) ----
// blocks [0, 516):       fold — li = bid/129, k = (bid%129)*4 + wave
// blocks [516, 516+6528): wtr  — flattened (c-tile, j-tile, li)
__global__ __launch_bounds__(256) void k_prep(
        const float* W1, const float* W2, const float* W3, const float* W4,
        const float* s1, const float* s2, const float* s3, const float* s4,
        const float* d1, const float* d2, const float* d3, const float* d4,
        float* __restrict__ fsAll, float* __restrict__ fdAll,
        u16* T1, u16* T2, u16* T3) {
    const int Ks[4] = {258, 516, 262, 136};
    const int Cs[4] = {512, 256, 128, 20};
    int bid = blockIdx.x;
    if (bid < 516) {
        // ---- fold: 4 waves, each one k-row; identical per-wave math to k_foldall ----
        int li = bid / 129;
        int k = (bid % 129) * 4 + (threadIdx.x >> 6);
        int lane = threadIdx.x & 63;
        if (k >= Ks[li]) return;
        const float* W  = (li == 0) ? W1 : (li == 1) ? W2 : (li == 2) ? W3 : W4;
        const float* as = (li == 0) ? s1 : (li == 1) ? s2 : (li == 2) ? s3 : s4;
        const float* ad = (li == 0) ? d1 : (li == 1) ? d2 : (li == 2) ? d3 : d4;
        int C = Cs[li];
        float s[8] = {0.f,0.f,0.f,0.f,0.f,0.f,0.f,0.f};
        float d[8] = {0.f,0.f,0.f,0.f,0.f,0.f,0.f,0.f};
        const float* wr = W + (size_t)k * 8 * C;
        for (int c = lane; c < C; c += 64) {
            #pragma unroll
            for (int h = 0; h < 8; ++h) {
                float w = wr[h * C + c];
                s[h] += w * as[h * C + c];
                d[h] += w * ad[h * C + c];
            }
        }
        #pragma unroll
        for (int off = 32; off >= 1; off >>= 1) {
            #pragma unroll
            for (int h = 0; h < 8; ++h) {
                s[h] += __shfl_xor(s[h], off);
                d[h] += __shfl_xor(d[h], off);
            }
        }
        if (lane == 0) {
            float* fo = fsAll + (size_t)li * 516 * 8 + k * 8;
            float* go = fdAll + (size_t)li * 516 * 8 + k * 8;
            #pragma unroll
            for (int h = 0; h < 8; ++h) { fo[h] = s[h]; go[h] = d[h]; }
        }
    } else {
        // ---- wtr: Wt2[c, h*Kp+k] = W[k, h*C+c] (bf16) ----
        const int Kps[3] = {288, 544, 288};
        int w = bid - 516;
        int li = w / (16 * 136);
        int rem = w % (16 * 136);
        int c0 = (rem % 16) * 32;
        int j0 = (rem / 16) * 32;
        int C = Cs[li], K = Ks[li], Kp = Kps[li], KK = 8 * Kp;
        if (c0 >= C || j0 >= KK) return;
        const float* W = (li == 0) ? W1 : (li == 1) ? W2 : W3;
        u16* Wt2 = (li == 0) ? T1 : (li == 1) ? T2 : T3;
        __shared__ float tile[32][33];
        int h = j0 / Kp, k0 = j0 % Kp;
        int tid = threadIdx.x;
        for (int idx = tid; idx < 1024; idx += 256) {
            int kr = idx >> 5, cc = idx & 31;
            int gk = k0 + kr;
            tile[kr][cc] = (gk < K) ? W[(size_t)gk * (8 * C) + h * C + c0 + cc] : 0.f;
        }
        __syncthreads();
        for (int idx = tid; idx < 1024; idx += 256) {
            int cr = idx >> 5, kc = idx & 31;
            Wt2[(size_t)(c0 + cr) * KK + j0 + kc] = f2bf(tile[kc][cr]);
        }
    }
}

// ---------------- k_mf: block per node.
//  L1 (biasp==null): feat = selu(data@W0+b0) inline; coords from data.
//  Lk: feat = selu((sum_z bf16 facc partials)*0.125 + bias)
//  writes afb bf16 row; es/ed = sum_c af[n,c]*{fs,fd}[c,:] in fp32 ----------------
__global__ __launch_bounds__(256) void k_mf(const float* p0, const float* p1,
                                            const float* p2, const float* p3, int np,
                                            const float* __restrict__ data,
                                            const float* __restrict__ W0,
                                            const float* __restrict__ b0,
                                            const u16* __restrict__ facc,
                                            const float* __restrict__ biasp,
                                            int split, int MN, int FC, int K, int Kp,
                                            const float* __restrict__ fs,
                                            const float* __restrict__ fd,
                                            u16* __restrict__ afb,
                                            float* __restrict__ es, float* __restrict__ ed,
                                            float* __restrict__ c0out) {
    int n = blockIdx.x, t = threadIdx.x;
    __shared__ float drow[10];
    bool l1 = (biasp == nullptr);
    if (l1 && t < 10) drow[t] = data[n * 10 + t];
    __syncthreads();
    float pes[8] = {0.f,0.f,0.f,0.f,0.f,0.f,0.f,0.f};
    float ped[8] = {0.f,0.f,0.f,0.f,0.f,0.f,0.f,0.f};
    u16* rowb = afb + (size_t)n * Kp;
    for (int cf = t; cf < FC; cf += 256) {
        float v;
        if (l1) {
            v = b0[cf];
            #pragma unroll
            for (int k = 0; k < 10; ++k) v += drow[k] * W0[k * 256 + cf];
            v = selu_f(v);
        } else {
            float s = 0.f;
            for (int z = 0; z < split; ++z)
                s += bf2f(facc[(size_t)z * MN + (size_t)n * FC + cf]);
            v = selu_f(s * 0.125f + biasp[cf]);
        }
        int c = 2 * np + cf;
        rowb[c] = f2bf(v);
        const float* fsr = fs + c * 8;
        const float* fdr = fd + c * 8;
        #pragma unroll
        for (int h = 0; h < 8; ++h) { pes[h] += v * fsr[h]; ped[h] += v * fdr[h]; }
    }
    if (t < 2 * np) {
        float v;
        if (l1) {
            v = drow[t];
            c0out[n * 2 + t] = v;
        } else {
            const float* p = (t < 2) ? p0 : (t < 4) ? p1 : (t < 6) ? p2 : p3;
            v = p[n * 2 + (t & 1)];
        }
        rowb[t] = f2bf(v);
        #pragma unroll
        for (int h = 0; h < 8; ++h) { pes[h] += v * fs[t * 8 + h]; ped[h] += v * fd[t * 8 + h]; }
    }
    for (int c = K + t; c < Kp; c += 256) rowb[c] = 0;
    #pragma unroll
    for (int off = 32; off >= 1; off >>= 1) {
        #pragma unroll
        for (int h = 0; h < 8; ++h) {
            pes[h] += __shfl_xor(pes[h], off);
            ped[h] += __shfl_xor(ped[h], off);
        }
    }
    __shared__ float red[4][16];
    int wv = t >> 6, ln = t & 63;
    if (ln == 0) {
        #pragma unroll
        for (int h = 0; h < 8; ++h) { red[wv][h] = pes[h]; red[wv][8 + h] = ped[h]; }
    }
    __syncthreads();
    if (t < 16) {
        float s = red[0][t] + red[1][t] + red[2][t] + red[3][t];
        if (t < 8) es[n * 8 + t] = s;
        else       ed[n * 8 + (t - 8)] = s;
    }
}

// ---------------- fused softmax + gather + coords: block per dst node ----------------
template <int S32>
__global__ __launch_bounds__(256) void k_gag(const float* __restrict__ es,
                            const float* __restrict__ ed,
                            const int* __restrict__ rowp, const int* __restrict__ ssrc,
                            const float* __restrict__ cprev, const u16* __restrict__ afb,
                            u16* __restrict__ g, float* __restrict__ cnext, int Kp) {
    __shared__ int   ls[128];
    __shared__ float la[128 * 8];
    __shared__ float lc0[128], lc1[128], lw[128];
    __shared__ float linv[8];
    int n = blockIdx.x, t = threadIdx.x;
    int s0 = rowp[n];
    int deg = rowp[n + 1] - s0;
    if (deg > 128) deg = 128;
    for (int i = t; i < deg; i += 256) {
        int src = ssrc[s0 + i];
        ls[i] = src;
        lc0[i] = cprev[src * 2];
        lc1[i] = cprev[src * 2 + 1];
    }
    __syncthreads();
    for (int i = t; i < deg * 8; i += 256) {
        int e = i >> 3, h = i & 7;
        float x = es[ls[e] * 8 + h] + ed[n * 8 + h];
        la[i] = x > 0.f ? x : 0.2f * x;
    }
    __syncthreads();
    if (t < 8) {
        float m = -1e30f;
        for (int e = 0; e < deg; ++e) m = fmaxf(m, la[e * 8 + t]);
        float s = 0.f;
        for (int e = 0; e < deg; ++e) {
            float v = __expf(la[e * 8 + t] - m);
            la[e * 8 + t] = v;
            s += v;
        }
        linv[t] = 1.f / s;
    }
    __syncthreads();
    for (int i = t; i < deg; i += 256) {
        float w = 0.f;
        #pragma unroll
        for (int h = 0; h < 8; ++h) w += la[i * 8 + h] * linv[h];
        lw[i] = w;
    }
    int nW = Kp >> 1;
    float acc[8][2 * S32];
    #pragma unroll
    for (int h = 0; h < 8; ++h)
        #pragma unroll
        for (int s = 0; s < 2 * S32; ++s) acc[h][s] = 0.f;
    int e = 0;
    for (; e + 1 < deg; e += 2) {
        const unsigned* r0 = (const unsigned*)(afb + (size_t)ls[e] * Kp);
        const unsigned* r1 = (const unsigned*)(afb + (size_t)ls[e + 1] * Kp);
        unsigned v0[S32], v1[S32];
        #pragma unroll
        for (int s = 0; s < S32; ++s) {
            int w = t + 256 * s;
            v0[s] = (w < nW) ? r0[w] : 0u;
            v1[s] = (w < nW) ? r1[w] : 0u;
        }
        float a0[8], a1[8];
        #pragma unroll
        for (int h = 0; h < 8; ++h) { a0[h] = la[e * 8 + h]; a1[h] = la[(e + 1) * 8 + h]; }
        #pragma unroll
        for (int s = 0; s < S32; ++s) {
            float x0 = bf2f(v0[s] & 0xffff), y0 = bf2f(v0[s] >> 16);
            float x1 = bf2f(v1[s] & 0xffff), y1 = bf2f(v1[s] >> 16);
            #pragma unroll
            for (int h = 0; h < 8; ++h) {
                acc[h][2 * s]     += a0[h] * x0 + a1[h] * x1;
                acc[h][2 * s + 1] += a0[h] * y0 + a1[h] * y1;
            }
        }
    }
    if (e < deg) {
        const unsigned* r0 = (const unsigned*)(afb + (size_t)ls[e] * Kp);
        unsigned v0[S32];
        #pragma unroll
        for (int s = 0; s < S32; ++s) {
            int w = t + 256 * s;
            v0[s] = (w < nW) ? r0[w] : 0u;
        }
        float a0[8];
        #pragma unroll
        for (int h = 0; h < 8; ++h) a0[h] = la[e * 8 + h];
        #pragma unroll
        for (int s = 0; s < S32; ++s) {
            float x0 = bf2f(v0[s] & 0xffff), y0 = bf2f(v0[s] >> 16);
            #pragma unroll
            for (int h = 0; h < 8; ++h) {
                acc[h][2 * s]     += a0[h] * x0;
                acc[h][2 * s + 1] += a0[h] * y0;
            }
        }
    }
    unsigned* grw = (unsigned*)(g + (size_t)n * 8 * Kp);
    #pragma unroll
    for (int s = 0; s < S32; ++s) {
        int w = t + 256 * s;
        if (w < nW) {
            #pragma unroll
            for (int h = 0; h < 8; ++h) {
                float iv = linv[h];
                unsigned lo = f2bf(acc[h][2 * s] * iv);
                unsigned hi = f2bf(acc[h][2 * s + 1] * iv);
                grw[h * nW + w] = lo | (hi << 16);
            }
        }
    }
    __syncthreads();
    if (t == 0) {
        float oc0 = 0.f, oc1 = 0.f;
        for (int i = 0; i < deg; ++i) { oc0 += lw[i] * lc0[i]; oc1 += lw[i] * lc1[i]; }
        oc0 *= 0.025f; oc1 *= 0.025f;
        float a0 = cprev[n * 2], a1 = cprev[n * 2 + 1];
        cnext[n * 2]     = (a0 == 0.f) ? 0.f : ((a0 == 1.f) ? 1.f : oc0);
        cnext[n * 2 + 1] = (a1 == 1.f) ? 1.f : ((a1 == 0.f) ? 0.f : oc1);
    }
}

// ---------------- split-K MFMA GEMM, 128x128 tile: facc16[z] = bf16 partial of g @ Wt2^T ----------------
__global__ __launch_bounds__(256) void k_gemm_s(const u16* __restrict__ A,   // [M, KK]
                                                const u16* __restrict__ Bt,  // [NC, KK]
                                                u16* __restrict__ facc16,    // [split][M*NC] bf16
                                                int M, int KK, int NC, int kchunk, int MN) {
    __shared__ u16 As[128 * 32];
    __shared__ u16 Bs[128 * 32];
    int tid = threadIdx.x;
    int wave = tid >> 6, lane = tid & 63;
    int bm = blockIdx.y * 128, bn = blockIdx.x * 128, z = blockIdx.z;
    int kbeg = z * kchunk, kend = min(KK, kbeg + kchunk);
    int wm = (wave >> 1) * 64, wn = (wave & 1) * 64;
    int l16 = lane & 15, q = lane >> 4;
    f32x4 acc[4][4] = {};
    for (int k0 = kbeg; k0 < kend; k0 += 32) {
        #pragma unroll
        for (int it = 0; it < 2; ++it) {
            int seg = tid + it * 256;
            int row = seg >> 2, sq = seg & 3;
            uint4 va = {0u, 0u, 0u, 0u};
            int grow = bm + row;
            if (grow < M) va = *(const uint4*)(A + (size_t)grow * KK + k0 + sq * 8);
            *(uint4*)(As + row * 32 + ((sq ^ (row & 3)) * 8)) = va;
            uint4 vb = *(const uint4*)(Bt + (size_t)(bn + row) * KK + k0 + sq * 8);
            *(uint4*)(Bs + row * 32 + ((sq ^ (row & 3)) * 8)) = vb;
        }
        __syncthreads();
        bf16x8 fa[4], fb[4];
        #pragma unroll
        for (int mi = 0; mi < 4; ++mi) {
            int row = wm + mi * 16 + l16;
            fa[mi] = *(const bf16x8*)(As + row * 32 + ((q ^ (row & 3)) * 8));
            int col = wn + mi * 16 + l16;
            fb[mi] = *(const bf16x8*)(Bs + col * 32 + ((q ^ (col & 3)) * 8));
        }
        #pragma unroll
        for (int mi = 0; mi < 4; ++mi)
            #pragma unroll
            for (int ni = 0; ni < 4; ++ni)
                acc[mi][ni] = __builtin_amdgcn_mfma_f32_16x16x32_bf16(fa[mi], fb[ni], acc[mi][ni], 0, 0, 0);
        __syncthreads();
    }
    u16* out = facc16 + (size_t)z * MN;
    #pragma unroll
    for (int mi = 0; mi < 4; ++mi) {
        int row0 = bm + wm + mi * 16 + q * 4;
        #pragma unroll
        for (int ni = 0; ni < 4; ++ni) {
            int col = bn + wn + ni * 16 + l16;
            #pragma unroll
            for (int r = 0; r < 4; ++r) {
                int row = row0 + r;
                if (row < M) out[(size_t)row * NC + col] = f2bf(acc[mi][ni][r]);
            }
        }
    }
}

// ---------------- layer 4: fused softmax + coords -> output (wave per node) ----------------
__global__ void k_final(const float* __restrict__ es, const float* __restrict__ ed,
                        const int* __restrict__ rowp, const int* __restrict__ ssrc,
                        const float* __restrict__ cprev, float* __restrict__ outp) {
    int wid = (blockIdx.x * blockDim.x + threadIdx.x) >> 6;
    int lane = threadIdx.x & 63;
    if (wid >= N_NODES) return;
    int n = wid;
    int s0 = rowp[n], deg = rowp[n + 1] - s0;
    int h = lane & 7, ei = lane >> 3;
    float edh = ed[n * 8 + h];
    float m = -1e30f;
    for (int b = 0; b < deg; b += 8) {
        int e = b + ei;
        if (e < deg) {
            int src = ssrc[s0 + e];
            float x = es[src * 8 + h] + edh;
            x = x > 0.f ? x : 0.2f * x;
            m = fmaxf(m, x);
        }
    }
    m = fmaxf(m, __shfl_xor(m, 8));
    m = fmaxf(m, __shfl_xor(m, 16));
    m = fmaxf(m, __shfl_xor(m, 32));
    float ssum = 0.f;
    for (int b = 0; b < deg; b += 8) {
        int e = b + ei;
        if (e < deg) {
            int src = ssrc[s0 + e];
            float x = es[src * 8 + h] + edh;
            x = x > 0.f ? x : 0.2f * x;
            ssum += __expf(x - m);
        }
    }
    ssum += __shfl_xor(ssum, 8);
    ssum += __shfl_xor(ssum, 16);
    ssum += __shfl_xor(ssum, 32);
    float inv = 1.f / ssum;
    float oc0 = 0.f, oc1 = 0.f;
    for (int b = 0; b < deg; b += 8) {
        int e = b + ei;
        if (e < deg) {
            int src = ssrc[s0 + e];
            float x = es[src * 8 + h] + edh;
            x = x > 0.f ? x : 0.2f * x;
            float w = __expf(x - m) * inv;
            w += __shfl_xor(w, 1);
            w += __shfl_xor(w, 2);
            w += __shfl_xor(w, 4);
            if (h == 0) {
                oc0 += w * cprev[src * 2];
                oc1 += w * cprev[src * 2 + 1];
            }
        }
    }
    oc0 += __shfl_xor(oc0, 8);  oc1 += __shfl_xor(oc1, 8);
    oc0 += __shfl_xor(oc0, 16); oc1 += __shfl_xor(oc1, 16);
    oc0 += __shfl_xor(oc0, 32); oc1 += __shfl_xor(oc1, 32);
    if (lane == 0) {
        oc0 *= 0.025f; oc1 *= 0.025f;
        float a0 = cprev[n * 2], a1 = cprev[n * 2 + 1];
        outp[n * 2]     = (a0 == 0.f) ? 0.f : ((a0 == 1.f) ? 1.f : oc0);
        outp[n * 2 + 1] = (a1 == 1.f) ? 1.f : ((a1 == 0.f) ? 0.f : oc1);
    }
}

extern "C" void kernel_launch(void* const* d_in, const int* in_sizes, int n_in,
                              void* d_out, int out_size, void* d_ws, size_t ws_size,
                              hipStream_t stream) {
    const float* data = (const float*)d_in[0];
    const int* ei = (const int*)d_in[1];
    const float* W0 = (const float*)d_in[2];
    const float* b0 = (const float*)d_in[3];
    int E = in_sizes[1] / 2;
    int Esz = E + N_NODES;

    char* wp = (char*)d_ws;
    size_t off = 0;
    auto alloc = [&](size_t bytes) {
        void* p = wp + off;
        off += (bytes + 1023) & ~(size_t)1023;
        return p;
    };
    u16*   g     = (u16*)alloc((size_t)N_NODES * 8 * 576 * 2);
    u16*   T1    = (u16*)alloc((size_t)512 * 8 * 288 * 2);
    u16*   T2    = (u16*)alloc((size_t)256 * 8 * 544 * 2);
    u16*   T3    = (u16*)alloc((size_t)128 * 8 * 288 * 2);
    u16*   facc  = (u16*)alloc((size_t)8 * N_NODES * 512 * 2);   // bf16 split partials
    u16*   afb   = (u16*)alloc((size_t)N_NODES * 576 * 2);
    float* es    = (float*)alloc((size_t)N_NODES * 8 * 4);
    float* ebd   = (float*)alloc((size_t)N_NODES * 8 * 4);
    float* fsAll = (float*)alloc((size_t)4 * 516 * 8 * 4);
    float* fdAll = (float*)alloc((size_t)4 * 516 * 8 * 4);
    float* c0    = (float*)alloc(N_NODES * 2 * 4);
    float* c1    = (float*)alloc(N_NODES * 2 * 4);
    float* c2    = (float*)alloc(N_NODES * 2 * 4);
    float* c3    = (float*)alloc(N_NODES * 2 * 4);
    int* cnt  = (int*)alloc(N_NODES * 2 * 4);   // cnt + cur, one memset
    int* cur  = cnt + N_NODES;
    int* rowp = (int*)alloc((N_NODES + 1) * 4);
    int* ssrc = (int*)alloc(Esz * 4);

    hipMemsetAsync(cnt, 0, N_NODES * 2 * 4, stream);
    int gE = (Esz + 255) / 256;
    k_count<<<gE, 256, 0, stream>>>(ei, cnt, E, Esz);
    k_scan<<<1, 256, 0, stream>>>(cnt, rowp, N_NODES);
    k_fill<<<gE, 256, 0, stream>>>(ei, rowp, cur, ssrc, E, Esz);

    struct LP { const float *W, *as, *ad, *bs; int K, C, split; };
    LP L[4] = {
        {(const float*)d_in[4],  (const float*)d_in[5],  (const float*)d_in[6],  (const float*)d_in[7],  258, 512, 4},
        {(const float*)d_in[8],  (const float*)d_in[9],  (const float*)d_in[10], (const float*)d_in[11], 516, 256, 8},
        {(const float*)d_in[12], (const float*)d_in[13], (const float*)d_in[14], (const float*)d_in[15], 262, 128, 8},
        {(const float*)d_in[16], (const float*)d_in[17], (const float*)d_in[18], (const float*)d_in[19], 136, 20, 1},
    };
    k_prep<<<516 + 16 * 136 * 3, 256, 0, stream>>>(
        L[0].W, L[1].W, L[2].W, L[3].W,
        L[0].as, L[1].as, L[2].as, L[3].as,
        L[0].ad, L[1].ad, L[2].ad, L[3].ad,
        fsAll, fdAll, T1, T2, T3);

    float* cbuf[4] = {c0, c1, c2, c3};
    u16* Tb[3] = {T1, T2, T3};
    int FC[4] = {256, 512, 256, 128};   // feat width consumed by layer li

    for (int li = 0; li < 4; ++li) {
        LP& lp = L[li];
        const float* p[4] = {nullptr, nullptr, nullptr, nullptr};
        for (int j = 0; j <= li; ++j) p[j] = cbuf[li - j];
        int Kp = ((lp.K + 31) / 32) * 32;
        int KK = 8 * Kp;
        const float* biasp = (li == 0) ? nullptr : L[li - 1].bs;
        int splitp = (li == 0) ? 1 : L[li - 1].split;
        int MNp = N_NODES * FC[li];
        const float* fs = fsAll + (size_t)li * 516 * 8;
        const float* fd = fdAll + (size_t)li * 516 * 8;

        k_mf<<<N_NODES, 256, 0, stream>>>(p[0], p[1], p[2], p[3], li + 1,
                                          data, W0, b0, facc, biasp, splitp, MNp, FC[li],
                                          lp.K, Kp, fs, fd, afb, es, ebd, c0);
        if (li < 3) {
            if ((Kp >> 1) <= 256)
                k_gag<1><<<N_NODES, 256, 0, stream>>>(es, ebd, rowp, ssrc, cbuf[li], afb,
                                                      g, cbuf[li + 1], Kp);
            else
                k_gag<2><<<N_NODES, 256, 0, stream>>>(es, ebd, rowp, ssrc, cbuf[li], afb,
                                                      g, cbuf[li + 1], Kp);
            int MN = N_NODES * lp.C;
            k_gemm_s<<<dim3(lp.C / 128, (N_NODES + 127) / 128, lp.split), 256, 0, stream>>>(
                g, Tb[li], facc, N_NODES, KK, lp.C, KK / lp.split, MN);
        } else {
            k_final<<<(N_NODES + 3) / 4, 256, 0, stream>>>(es, ebd, rowp, ssrc, cbuf[3],
                                                           (float*)d_out);
        }
    }
}